// Round 6
// baseline (298.252 us; speedup 1.0000x reference)
//
#include <hip/hip_runtime.h>

// LocallyConnected2D: out[b,p,f] = sum_k x_patch[b,p,k] * kernel[p,k,f] + bias[p,f]
// B=16, H=W=64, C=32, KH=KW=3, OH=OW=62, P=3844, F=64, fp32.
//
// Memory-bound on the 283 MB weight stream (read exactly once; all 16
// batches accumulate in registers).
// R5: K-slice geometry. One wave per p (3844 waves, ~15/CU = 4x R0's TLP).
// lane = (rg, fq): fq = lane&15 owns f-quad, rg = lane>>4 owns 18 of the 72
// (pos,c4) K-units. Weight loads stay 1KB-distinct/instr (4 rg x 16 fq x
// 16B, rows 1KB apart) -- R4's mistake (b-split -> 256B/instr broadcast)
// fixed. End: reduce-scatter over rg via __shfl_xor(16/32), compile-time
// acc indexing only (R2 spill lesson); rg selects via cndmask, and picks
// which 4 batches this lane stores.
// Evidence: R0/R3 both 81us (3.7 TB/s) regardless of x-path => in-flight
// weight bytes/CU is the limiter; more waves with intact coalescing is the fix.
// Lessons: R1 = no provably wave-uniform x addrs (scalarizes to s_load).
// R2 = no runtime-indexed register arrays (scratch spill, 911MB writes).

namespace {
constexpr int Hc = 64, Wc = 64, Cc = 32;
constexpr int OWc = 62;
constexpr int Pc = 62 * 62;        // 3844
constexpr int Fc = 64;
constexpr int KFc = 288 * 64;      // K*F per position
constexpr size_t XB = (size_t)Hc * Wc * Cc;  // per-batch x stride (floats)
}

#define FMA4(A, XV)                                                             \
    A.x = fmaf(XV.x, kv0.x, fmaf(XV.y, kv1.x, fmaf(XV.z, kv2.x, fmaf(XV.w, kv3.x, A.x)))); \
    A.y = fmaf(XV.x, kv0.y, fmaf(XV.y, kv1.y, fmaf(XV.z, kv2.y, fmaf(XV.w, kv3.y, A.y)))); \
    A.z = fmaf(XV.x, kv0.z, fmaf(XV.y, kv1.z, fmaf(XV.z, kv2.z, fmaf(XV.w, kv3.z, A.z)))); \
    A.w = fmaf(XV.x, kv0.w, fmaf(XV.y, kv1.w, fmaf(XV.z, kv2.w, fmaf(XV.w, kv3.w, A.w))));

__global__ __launch_bounds__(256, 4)
void lc2d(const float* __restrict__ x, const float* __restrict__ kern,
          const float* __restrict__ bias, float* __restrict__ out)
{
    const int t    = threadIdx.x;
    const int lane = t & 63;
    const int wid  = t >> 6;
    const int fq   = lane & 15;
    const int f0   = fq << 2;
    const int rg   = lane >> 4;        // K-slice 0..3

    const int p  = blockIdx.x * 4 + wid;   // grid exactly P/4
    const int oh = p / OWc;
    const int ow = p - oh * OWc;

    const float* kbase = kern + (size_t)p * KFc + f0;
    const float* xbase = x + ((size_t)oh * Wc + ow) * Cc;

    float4 acc[16];
    #pragma unroll
    for (int b = 0; b < 16; ++b) acc[b] = make_float4(0.f, 0.f, 0.f, 0.f);

    // 72 K-units: u = (pos<<3)|c4, pos=kh*3+kw in 0..8, c4 in 0..7.
    // k-row base of unit u is 4*u, so kernel offset = u*256 floats (+f0).
    // Thread rg handles u = rg, rg+4, ..., rg+68 (18 units).
    #pragma unroll
    for (int i = 0; i < 18; ++i) {
        const int u   = rg + 4 * i;
        const int pos = u >> 3;
        const int c4  = u & 7;
        const int kh  = (pos * 11) >> 5;   // pos/3 for pos<=8
        const int kw  = pos - kh * 3;

        const float* kk = kbase + (size_t)u * 256;
        const float4 kv0 = *(const float4*)(kk + 0 * Fc);
        const float4 kv1 = *(const float4*)(kk + 1 * Fc);
        const float4 kv2 = *(const float4*)(kk + 2 * Fc);
        const float4 kv3 = *(const float4*)(kk + 3 * Fc);

        const float* xk = xbase + (size_t)(kh * Wc + kw) * Cc + c4 * 4;
        #pragma unroll
        for (int b4 = 0; b4 < 4; ++b4) {
            const float4 xv0 = *(const float4*)(xk + (size_t)(4 * b4 + 0) * XB);
            const float4 xv1 = *(const float4*)(xk + (size_t)(4 * b4 + 1) * XB);
            const float4 xv2 = *(const float4*)(xk + (size_t)(4 * b4 + 2) * XB);
            const float4 xv3 = *(const float4*)(xk + (size_t)(4 * b4 + 3) * XB);
            FMA4(acc[4 * b4 + 0], xv0);
            FMA4(acc[4 * b4 + 1], xv1);
            FMA4(acc[4 * b4 + 2], xv2);
            FMA4(acc[4 * b4 + 3], xv3);
        }
    }

    // Reduce-scatter across the 4 rg slices (compile-time indexing only).
    const int hi  = rg & 1;
    const int hi2 = (rg >> 1) & 1;

    float4 kept[8];   // b = hi*8 + j, summed over rg pairs {rg, rg^1}
    #pragma unroll
    for (int j = 0; j < 8; ++j) {
        float4 keep = hi ? acc[j + 8] : acc[j];
        float4 send = hi ? acc[j]     : acc[j + 8];
        send.x = __shfl_xor(send.x, 16);
        send.y = __shfl_xor(send.y, 16);
        send.z = __shfl_xor(send.z, 16);
        send.w = __shfl_xor(send.w, 16);
        kept[j] = make_float4(keep.x + send.x, keep.y + send.y,
                              keep.z + send.z, keep.w + send.w);
    }

    float4 fin[4];    // b = hi*8 + hi2*4 + j, summed over all 4 rg
    #pragma unroll
    for (int j = 0; j < 4; ++j) {
        float4 keep = hi2 ? kept[j + 4] : kept[j];
        float4 send = hi2 ? kept[j]     : kept[j + 4];
        send.x = __shfl_xor(send.x, 32);
        send.y = __shfl_xor(send.y, 32);
        send.z = __shfl_xor(send.z, 32);
        send.w = __shfl_xor(send.w, 32);
        fin[j] = make_float4(keep.x + send.x, keep.y + send.y,
                             keep.z + send.z, keep.w + send.w);
    }

    const float4 bv = *(const float4*)(bias + (size_t)p * Fc + f0);
    const int bbase = (hi << 3) | (hi2 << 2);
    #pragma unroll
    for (int j = 0; j < 4; ++j) {
        const float4 o = make_float4(fin[j].x + bv.x, fin[j].y + bv.y,
                                     fin[j].z + bv.z, fin[j].w + bv.w);
        *(float4*)(out + ((size_t)(bbase + j) * Pc + p) * Fc + f0) = o;
    }
}

extern "C" void kernel_launch(void* const* d_in, const int* in_sizes, int n_in,
                              void* d_out, int out_size, void* d_ws, size_t ws_size,
                              hipStream_t stream)
{
    const float* x    = (const float*)d_in[0];
    const float* kern = (const float*)d_in[1];
    const float* bias = (const float*)d_in[2];
    float* out = (float*)d_out;
    dim3 grid(Pc / 4);   // 961 blocks, 1 wave per p
    lc2d<<<grid, 256, 0, stream>>>(x, kern, bias, out);
}

// Round 7
// 77.950 us; speedup vs baseline: 3.8262x; 3.8262x over previous
//
#include <hip/hip_runtime.h>

// LocallyConnected2D: out[b,p,f] = sum_k x_patch[b,p,k] * kernel[p,k,f] + bias[p,f]
// B=16, H=W=64, C=32, KH=KW=3, OH=OW=62, P=3844, F=64, fp32.
//
// Memory-bound on the 283 MB weight stream (read exactly once; all 16
// batches accumulate in registers).
// Geometry (R5): one wave per p (3844 waves, ~15/CU). lane = (rg, fq):
// fq = lane&15 owns f-quad, rg = lane>>4 owns 18 of 72 (pos,c4) K-units.
// Weight loads are 1KB-distinct per instr (4 rg x 16 fq x 16B, 4KB/step
// contiguous). Tail: reduce-scatter over rg via __shfl_xor(16/32),
// compile-time register indexing only.
// R6 fix vs R5: launch_bounds(256,2) [R5's (256,4) forced VGPR=64 -> acc
// spill, 460MB scratch writes] and unroll 3 (not full 18) so the scheduler
// can't hoist 360 loads into live ranges past the cap [R2's spill driver].
// Lessons: R1 = no provably wave-uniform x addrs (s_load serialization).
// R2/R5 = spill tripwire is WRITE_SIZE >> 15.4 MB.

namespace {
constexpr int Hc = 64, Wc = 64, Cc = 32;
constexpr int OWc = 62;
constexpr int Pc = 62 * 62;        // 3844
constexpr int Fc = 64;
constexpr int KFc = 288 * 64;      // K*F per position
constexpr size_t XB = (size_t)Hc * Wc * Cc;  // per-batch x stride (floats)
}

#define FMA4(A, XV)                                                             \
    A.x = fmaf(XV.x, kv0.x, fmaf(XV.y, kv1.x, fmaf(XV.z, kv2.x, fmaf(XV.w, kv3.x, A.x)))); \
    A.y = fmaf(XV.x, kv0.y, fmaf(XV.y, kv1.y, fmaf(XV.z, kv2.y, fmaf(XV.w, kv3.y, A.y)))); \
    A.z = fmaf(XV.x, kv0.z, fmaf(XV.y, kv1.z, fmaf(XV.z, kv2.z, fmaf(XV.w, kv3.z, A.z)))); \
    A.w = fmaf(XV.x, kv0.w, fmaf(XV.y, kv1.w, fmaf(XV.z, kv2.w, fmaf(XV.w, kv3.w, A.w))));

__global__ __launch_bounds__(256, 2)
void lc2d(const float* __restrict__ x, const float* __restrict__ kern,
          const float* __restrict__ bias, float* __restrict__ out)
{
    const int t    = threadIdx.x;
    const int lane = t & 63;
    const int wid  = t >> 6;
    const int fq   = lane & 15;
    const int f0   = fq << 2;
    const int rg   = lane >> 4;        // K-slice 0..3

    const int p  = blockIdx.x * 4 + wid;   // grid exactly P/4
    const int oh = p / OWc;
    const int ow = p - oh * OWc;

    const float* kbase = kern + (size_t)p * KFc + f0;
    const float* xbase = x + ((size_t)oh * Wc + ow) * Cc;

    float4 acc[16];
    #pragma unroll
    for (int b = 0; b < 16; ++b) acc[b] = make_float4(0.f, 0.f, 0.f, 0.f);

    // 72 K-units: u = (pos<<3)|c4, pos=kh*3+kw in 0..8, c4 in 0..7.
    // kernel offset of unit u = u*256 floats (+f0). Thread rg handles
    // u = rg, rg+4, ..., rg+68 (18 units); the wave's 4 rg groups cover a
    // contiguous 4KB of kernel per step.
    #pragma unroll 3
    for (int i = 0; i < 18; ++i) {
        const int u   = rg + 4 * i;
        const int pos = u >> 3;
        const int c4  = u & 7;
        const int kh  = (pos * 11) >> 5;   // pos/3 for pos<=8
        const int kw  = pos - kh * 3;

        const float* kk = kbase + (size_t)u * 256;
        const float4 kv0 = *(const float4*)(kk + 0 * Fc);
        const float4 kv1 = *(const float4*)(kk + 1 * Fc);
        const float4 kv2 = *(const float4*)(kk + 2 * Fc);
        const float4 kv3 = *(const float4*)(kk + 3 * Fc);

        const float* xk = xbase + (size_t)(kh * Wc + kw) * Cc + c4 * 4;
        #pragma unroll
        for (int b4 = 0; b4 < 4; ++b4) {
            const float4 xv0 = *(const float4*)(xk + (size_t)(4 * b4 + 0) * XB);
            const float4 xv1 = *(const float4*)(xk + (size_t)(4 * b4 + 1) * XB);
            const float4 xv2 = *(const float4*)(xk + (size_t)(4 * b4 + 2) * XB);
            const float4 xv3 = *(const float4*)(xk + (size_t)(4 * b4 + 3) * XB);
            FMA4(acc[4 * b4 + 0], xv0);
            FMA4(acc[4 * b4 + 1], xv1);
            FMA4(acc[4 * b4 + 2], xv2);
            FMA4(acc[4 * b4 + 3], xv3);
        }
    }

    // Reduce-scatter across the 4 rg slices (compile-time indexing only).
    const int hi  = rg & 1;
    const int hi2 = (rg >> 1) & 1;

    float4 kept[8];   // b = hi*8 + j, summed over rg pairs {rg, rg^1}
    #pragma unroll
    for (int j = 0; j < 8; ++j) {
        float4 keep = hi ? acc[j + 8] : acc[j];
        float4 send = hi ? acc[j]     : acc[j + 8];
        send.x = __shfl_xor(send.x, 16);
        send.y = __shfl_xor(send.y, 16);
        send.z = __shfl_xor(send.z, 16);
        send.w = __shfl_xor(send.w, 16);
        kept[j] = make_float4(keep.x + send.x, keep.y + send.y,
                              keep.z + send.z, keep.w + send.w);
    }

    float4 fin[4];    // b = hi*8 + hi2*4 + j, summed over all 4 rg
    #pragma unroll
    for (int j = 0; j < 4; ++j) {
        float4 keep = hi2 ? kept[j + 4] : kept[j];
        float4 send = hi2 ? kept[j]     : kept[j + 4];
        send.x = __shfl_xor(send.x, 32);
        send.y = __shfl_xor(send.y, 32);
        send.z = __shfl_xor(send.z, 32);
        send.w = __shfl_xor(send.w, 32);
        fin[j] = make_float4(keep.x + send.x, keep.y + send.y,
                             keep.z + send.z, keep.w + send.w);
    }

    const float4 bv = *(const float4*)(bias + (size_t)p * Fc + f0);
    const int bbase = (hi << 3) | (hi2 << 2);
    #pragma unroll
    for (int j = 0; j < 4; ++j) {
        const float4 o = make_float4(fin[j].x + bv.x, fin[j].y + bv.y,
                                     fin[j].z + bv.z, fin[j].w + bv.w);
        *(float4*)(out + ((size_t)(bbase + j) * Pc + p) * Fc + f0) = o;
    }
}

extern "C" void kernel_launch(void* const* d_in, const int* in_sizes, int n_in,
                              void* d_out, int out_size, void* d_ws, size_t ws_size,
                              hipStream_t stream)
{
    const float* x    = (const float*)d_in[0];
    const float* kern = (const float*)d_in[1];
    const float* bias = (const float*)d_in[2];
    float* out = (float*)d_out;
    dim3 grid(Pc / 4);   // 961 blocks, 1 wave per p
    lc2d<<<grid, 256, 0, stream>>>(x, kern, bias, out);
}

// Round 8
// 55.296 us; speedup vs baseline: 5.3938x; 1.4097x over previous
//
#include <hip/hip_runtime.h>

// LocallyConnected2D: out[b,p,f] = sum_k x_patch[b,p,k] * kernel[p,k,f] + bias[p,f]
// B=16, H=W=64, C=32, KH=KW=3, OH=OW=62, P=3844, F=64, fp32 in/out.
//
// R7: MFMA. Evidence: R0/R3/R6 (three different fp32-FMA structures) all
// plateau at ~80us while R4 (same bytes, 4x the weight-load instrs) got
// WORSE -> we are VMEM-instruction-rate bound (20 mem-instrs per K-unit
// per wave, the 16 x-loads being 16-lane broadcasts of 16-64B distinct).
// MFMA operand layouts give 64 fully-distinct 16B fragments per instr:
// per p: A(x) 18 float4 loads (was 1152 broadcasts), B(W) 288 b32,
// 72 v_mfma_f32_16x16x16_f16, acc = 4 x f32x4. VMEM instrs/CU: 21.6K -> 4.9K.
// Weights still read exactly once (283MB = the 45us HBM floor).
// Shape: per p (one wave): M=16 batches, N=64 f (4 tiles of 16), K=288
// (9 pos x 2 halves of 16). f16 inputs + fp32 accumulate: max err ~3e-3
// vs 8.9e-2 threshold.
// v_mfma_f32_16x16x16_f16 layouts (canonical): A: row=lane&15,
// k=4*(lane>>4)+j. B: col=lane&15, k=4*(lane>>4)+j. D: col=lane&15,
// row=4*(lane>>4)+reg.
// Lessons: R1 = no provably wave-uniform x addrs; R2/R5 = spill tripwire
// is WRITE_SIZE >> 15.4MB (no runtime-indexed reg arrays, no tight
// launch_bounds cap); R4 = never narrow the distinct-bytes per VMEM instr.

typedef _Float16 f16x4 __attribute__((ext_vector_type(4)));
typedef float    f32x4 __attribute__((ext_vector_type(4)));

namespace {
constexpr int Wc = 64, Cc = 32;
constexpr int OWc = 62;
constexpr int Pc  = 3844;
constexpr int Fc  = 64;
constexpr int KFc = 288 * 64;
constexpr size_t XB = (size_t)64 * 64 * 32;   // per-batch x stride (floats)
}

#define BTILE(ACC, T)                                                       \
    {                                                                       \
        const float* wb = wh + (T) * 16;                                    \
        f16x4 bf;                                                           \
        bf[0] = (_Float16)wb[0 * Fc];                                       \
        bf[1] = (_Float16)wb[1 * Fc];                                       \
        bf[2] = (_Float16)wb[2 * Fc];                                       \
        bf[3] = (_Float16)wb[3 * Fc];                                       \
        ACC = __builtin_amdgcn_mfma_f32_16x16x16f16(a, bf, ACC, 0, 0, 0);   \
    }

__global__ __launch_bounds__(256)
void lc2d(const float* __restrict__ x, const float* __restrict__ kern,
          const float* __restrict__ bias, float* __restrict__ out)
{
    const int t    = threadIdx.x;
    const int lane = t & 63;
    const int wid  = t >> 6;
    const int lq   = lane & 15;        // A: batch row | B/D: f-col
    const int lg   = lane >> 4;        // k-group (and D row-group)

    const int p  = blockIdx.x * 4 + wid;   // grid exactly P/4 = 961
    const int oh = p / OWc;
    const int ow = p - oh * OWc;

    // A source: x[b=lq][oh+kh][ow+kw][c = h*16 + 4*lg + j]  (float4 per half)
    const float* xlane = x + (size_t)lq * XB + ((size_t)oh * Wc + ow) * Cc + 4 * lg;
    // B source: kern[p][k = pos*32 + h*16 + 4*lg + j][f = t16*16 + lq]
    const float* wlane = kern + (size_t)p * KFc + (size_t)(4 * lg) * Fc + lq;

    f32x4 acc0 = {0.f, 0.f, 0.f, 0.f};
    f32x4 acc1 = {0.f, 0.f, 0.f, 0.f};
    f32x4 acc2 = {0.f, 0.f, 0.f, 0.f};
    f32x4 acc3 = {0.f, 0.f, 0.f, 0.f};

    for (int pos = 0; pos < 9; ++pos) {
        const int kh = (pos * 11) >> 5;    // pos/3 for pos<=8
        const int kw = pos - kh * 3;
        const float* xp = xlane + (size_t)(kh * Wc + kw) * Cc;
        const float* wp = wlane + (size_t)(pos * 32) * Fc;

        // A fragments: two k-halves, one float4 each (per-lane distinct 16B)
        const float4 xa0 = *(const float4*)(xp);
        const float4 xa1 = *(const float4*)(xp + 16);
        f16x4 a0, a1;
        a0[0] = (_Float16)xa0.x; a0[1] = (_Float16)xa0.y;
        a0[2] = (_Float16)xa0.z; a0[3] = (_Float16)xa0.w;
        a1[0] = (_Float16)xa1.x; a1[1] = (_Float16)xa1.y;
        a1[2] = (_Float16)xa1.z; a1[3] = (_Float16)xa1.w;

        {   // half h = 0
            const float* wh = wp;
            const f16x4 a = a0;
            BTILE(acc0, 0) BTILE(acc1, 1) BTILE(acc2, 2) BTILE(acc3, 3)
        }
        {   // half h = 1
            const float* wh = wp + 16 * Fc;
            const f16x4 a = a1;
            BTILE(acc0, 0) BTILE(acc1, 1) BTILE(acc2, 2) BTILE(acc3, 3)
        }
    }

    // Epilogue: D row = batch 4*lg + r, col f = t16*16 + lq; add bias[p][f].
    const float b0 = bias[(size_t)p * Fc +  0 + lq];
    const float b1 = bias[(size_t)p * Fc + 16 + lq];
    const float b2 = bias[(size_t)p * Fc + 32 + lq];
    const float b3 = bias[(size_t)p * Fc + 48 + lq];
    #pragma unroll
    for (int r = 0; r < 4; ++r) {
        float* o = out + ((size_t)(4 * lg + r) * Pc + p) * Fc + lq;
        o[ 0] = acc0[r] + b0;
        o[16] = acc1[r] + b1;
        o[32] = acc2[r] + b2;
        o[48] = acc3[r] + b3;
    }
}

extern "C" void kernel_launch(void* const* d_in, const int* in_sizes, int n_in,
                              void* d_out, int out_size, void* d_ws, size_t ws_size,
                              hipStream_t stream)
{
    const float* x    = (const float*)d_in[0];
    const float* kern = (const float*)d_in[1];
    const float* bias = (const float*)d_in[2];
    float* out = (float*)d_out;
    dim3 grid(Pc / 4);   // 961 blocks, 1 wave per p
    lc2d<<<grid, 256, 0, stream>>>(x, kern, bias, out);
}